// Round 1
// baseline (574.808 us; speedup 1.0000x reference)
//
#include <hip/hip_runtime.h>

#define N_NODES 100000
#define N_EDGES 1250000
#define DIM 64
#define EDGE_DIM 10
#define BN_EPS 1e-5f

// workspace layout in floats
#define AGGR_OFF 0
#define SUM_OFF  6400000          // 64 floats: per-feature sum of ReLU output
#define SQ_OFF   (SUM_OFF + 64)   // 64 floats: per-feature sum of squares
#define SCALE_OFF (SUM_OFF + 128) // 64 floats: gamma * rsqrt(var+eps)
#define SHIFT_OFF (SUM_OFF + 192) // 64 floats: beta - mean*scale
#define MEMSET_FLOATS (SUM_OFF + 128)

// -----------------------------------------------------------------------------
// Edge kernel: one wave (64 lanes) per edge, lane = feature.
// msg = ReLU(x[src] + edge_attr @ W_edge + b_edge); atomicAdd into aggr[dst].
// -----------------------------------------------------------------------------
extern "C" __global__ __launch_bounds__(256)
void edge_msg_kernel(const float* __restrict__ x,
                     const int* __restrict__ ei,
                     const float* __restrict__ ea,
                     const float* __restrict__ We,
                     const float* __restrict__ be,
                     float* __restrict__ aggr)
{
    int lane = threadIdx.x & 63;
    int e = blockIdx.x * 4 + (threadIdx.x >> 6);
    e = __builtin_amdgcn_readfirstlane(e);   // wave-uniform -> scalar loads

    unsigned src = (unsigned)ei[e];
    unsigned dst = (unsigned)ei[N_EDGES + e];
    // defensive clamp (avoids OOB crash if index dtype ever surprises us)
    src = src < N_NODES ? src : (N_NODES - 1);
    dst = dst < N_NODES ? dst : (N_NODES - 1);

    size_t eb = (size_t)e * EDGE_DIM;
    float acc = be[lane];
    #pragma unroll
    for (int k = 0; k < EDGE_DIM; ++k) {
        // ea[eb+k] is wave-uniform -> s_load; We read is coalesced, L1-resident
        acc = fmaf(ea[eb + k], We[k * DIM + lane], acc);
    }
    float v = x[(size_t)src * DIM + lane] + acc;
    v = fmaxf(v, 0.0f);
    unsafeAtomicAdd(&aggr[(size_t)dst * DIM + lane], v);
}

// -----------------------------------------------------------------------------
// Node kernel: tiles of 64 nodes. h = x + aggr; t = ReLU(h@W1+b1);
// u = t@W2+b2; r = ReLU(u) -> out; accumulate per-feature sum/sumsq.
// Register-tiled 4x4 per thread; LDS tile stored transposed with pad 68.
// -----------------------------------------------------------------------------
extern "C" __global__ __launch_bounds__(256)
void node_mlp_kernel(const float* __restrict__ x,
                     const float* __restrict__ aggr,
                     const float* __restrict__ W1,
                     const float* __restrict__ b1,
                     const float* __restrict__ W2,
                     const float* __restrict__ b2,
                     float* __restrict__ out,
                     float* __restrict__ sums)
{
    __shared__ __align__(16) float sW1[DIM * DIM];
    __shared__ __align__(16) float sW2[DIM * DIM];
    __shared__ __align__(16) float sT[DIM * 68];   // [k][node], padded

    int tid = threadIdx.x;
    int base = blockIdx.x * 64;

    for (int i = tid; i < DIM * DIM; i += 256) {
        sW1[i] = W1[i];
        sW2[i] = W2[i];
    }

    // load H = x + aggr (float4 coalesced), store transposed into sT
    #pragma unroll
    for (int it = 0; it < 4; ++it) {
        int flat4 = it * 256 + tid;      // float4 index within 64x64 tile
        int node  = flat4 >> 4;
        int f0    = (flat4 & 15) * 4;
        int n     = base + node;
        float4 h4 = make_float4(0.f, 0.f, 0.f, 0.f);
        if (n < N_NODES) {
            float4 xv = *(const float4*)&x[(size_t)n * DIM + f0];
            float4 av = *(const float4*)&aggr[(size_t)n * DIM + f0];
            h4 = make_float4(xv.x + av.x, xv.y + av.y, xv.z + av.z, xv.w + av.w);
        }
        sT[(f0 + 0) * 68 + node] = h4.x;
        sT[(f0 + 1) * 68 + node] = h4.y;
        sT[(f0 + 2) * 68 + node] = h4.z;
        sT[(f0 + 3) * 68 + node] = h4.w;
    }
    __syncthreads();

    int i0 = (tid & 15) * 4;   // node sub-offset
    int j0 = (tid >> 4) * 4;   // feature sub-offset

    // ---- GEMM1: T = ReLU(H @ W1 + b1) ----
    float acc[4][4] = {};
    #pragma unroll 8
    for (int k = 0; k < DIM; ++k) {
        const float* ap = &sT[k * 68 + i0];
        const float* bp = &sW1[k * DIM + j0];
        float av[4] = {ap[0], ap[1], ap[2], ap[3]};
        float bv[4] = {bp[0], bp[1], bp[2], bp[3]};
        #pragma unroll
        for (int a = 0; a < 4; ++a)
            #pragma unroll
            for (int b = 0; b < 4; ++b)
                acc[a][b] = fmaf(av[a], bv[b], acc[a][b]);
    }
    __syncthreads();   // all GEMM1 reads of sT done before overwrite

    float4 b1v = *(const float4*)&b1[j0];
    float b1a[4] = {b1v.x, b1v.y, b1v.z, b1v.w};
    float tv[4][4];
    #pragma unroll
    for (int a = 0; a < 4; ++a)
        #pragma unroll
        for (int b = 0; b < 4; ++b)
            tv[a][b] = fmaxf(acc[a][b] + b1a[b], 0.0f);

    // write T transposed back into sT: sT[(j0+b)][i0..i0+3]
    #pragma unroll
    for (int b = 0; b < 4; ++b) {
        float4 w = make_float4(tv[0][b], tv[1][b], tv[2][b], tv[3][b]);
        *(float4*)&sT[(j0 + b) * 68 + i0] = w;
    }
    __syncthreads();

    // ---- GEMM2: R = ReLU(T @ W2 + b2) ----
    float acc2[4][4] = {};
    #pragma unroll 8
    for (int k = 0; k < DIM; ++k) {
        const float* ap = &sT[k * 68 + i0];
        const float* bp = &sW2[k * DIM + j0];
        float av[4] = {ap[0], ap[1], ap[2], ap[3]};
        float bv[4] = {bp[0], bp[1], bp[2], bp[3]};
        #pragma unroll
        for (int a = 0; a < 4; ++a)
            #pragma unroll
            for (int b = 0; b < 4; ++b)
                acc2[a][b] = fmaf(av[a], bv[b], acc2[a][b]);
    }

    float4 b2v = *(const float4*)&b2[j0];
    float b2a[4] = {b2v.x, b2v.y, b2v.z, b2v.w};
    float r[4][4];
    float ps[4] = {0.f, 0.f, 0.f, 0.f};
    float pq[4] = {0.f, 0.f, 0.f, 0.f};
    #pragma unroll
    for (int a = 0; a < 4; ++a) {
        int n = base + i0 + a;
        #pragma unroll
        for (int b = 0; b < 4; ++b)
            r[a][b] = fmaxf(acc2[a][b] + b2a[b], 0.0f);
        if (n < N_NODES) {
            float4 w = make_float4(r[a][0], r[a][1], r[a][2], r[a][3]);
            *(float4*)&out[(size_t)n * DIM + j0] = w;
            #pragma unroll
            for (int b = 0; b < 4; ++b) {
                ps[b] += r[a][b];
                pq[b] += r[a][b] * r[a][b];
            }
        }
    }

    // reduce over the 16 lanes sharing j0 (consecutive lanes within a wave)
    #pragma unroll
    for (int m = 1; m < 16; m <<= 1) {
        #pragma unroll
        for (int b = 0; b < 4; ++b) {
            ps[b] += __shfl_xor(ps[b], m, 64);
            pq[b] += __shfl_xor(pq[b], m, 64);
        }
    }
    if ((tid & 15) == 0) {
        #pragma unroll
        for (int b = 0; b < 4; ++b) {
            unsafeAtomicAdd(&sums[j0 + b], ps[b]);
            unsafeAtomicAdd(&sums[64 + j0 + b], pq[b]);
        }
    }
}

// -----------------------------------------------------------------------------
// BN stats: one block, 64 threads. scale/shift per feature.
// -----------------------------------------------------------------------------
extern "C" __global__ void bn_stats_kernel(float* __restrict__ sums,
                                           const float* __restrict__ gamma,
                                           const float* __restrict__ beta)
{
    int f = threadIdx.x;
    float inv_n = 1.0f / (float)N_NODES;
    float mean = sums[f] * inv_n;
    float var  = sums[64 + f] * inv_n - mean * mean;
    float sc   = gamma[f] * rsqrtf(var + BN_EPS);
    sums[128 + f] = sc;
    sums[192 + f] = beta[f] - mean * sc;
}

// -----------------------------------------------------------------------------
// BN apply: out = out*scale + shift, in place, float4.
// -----------------------------------------------------------------------------
extern "C" __global__ __launch_bounds__(256)
void bn_apply_kernel(float* __restrict__ out, const float* __restrict__ sums)
{
    int j = blockIdx.x * 256 + threadIdx.x;   // float4 index, 1.6M total
    int f0 = (j & 15) * 4;                    // (4j) % 64
    float4 sc = *(const float4*)&sums[128 + f0];
    float4 sh = *(const float4*)&sums[192 + f0];
    float4 v = ((float4*)out)[j];
    v.x = fmaf(v.x, sc.x, sh.x);
    v.y = fmaf(v.y, sc.y, sh.y);
    v.z = fmaf(v.z, sc.z, sh.z);
    v.w = fmaf(v.w, sc.w, sh.w);
    ((float4*)out)[j] = v;
}

extern "C" void kernel_launch(void* const* d_in, const int* in_sizes, int n_in,
                              void* d_out, int out_size, void* d_ws, size_t ws_size,
                              hipStream_t stream)
{
    const float* x     = (const float*)d_in[0];
    const int*   ei    = (const int*)  d_in[1];
    const float* ea    = (const float*)d_in[2];
    const float* We    = (const float*)d_in[3];
    const float* be    = (const float*)d_in[4];
    const float* W1    = (const float*)d_in[5];
    const float* b1    = (const float*)d_in[6];
    const float* W2    = (const float*)d_in[7];
    const float* b2    = (const float*)d_in[8];
    const float* gamma = (const float*)d_in[9];
    const float* beta  = (const float*)d_in[10];

    float* out  = (float*)d_out;
    float* ws   = (float*)d_ws;
    float* aggr = ws + AGGR_OFF;
    float* sums = ws + SUM_OFF;

    // zero aggr + sum/sumsq (scale/shift fully written later)
    hipMemsetAsync(ws, 0, (size_t)MEMSET_FLOATS * sizeof(float), stream);

    edge_msg_kernel<<<N_EDGES / 4, 256, 0, stream>>>(x, ei, ea, We, be, aggr);

    int node_blocks = (N_NODES + 63) / 64;   // 1563
    node_mlp_kernel<<<node_blocks, 256, 0, stream>>>(x, aggr, W1, b1, W2, b2, out, sums);

    bn_stats_kernel<<<1, 64, 0, stream>>>(sums, gamma, beta);

    bn_apply_kernel<<<(N_NODES * DIM / 4) / 256, 256, 0, stream>>>(out, sums);
}

// Round 2
// 541.445 us; speedup vs baseline: 1.0616x; 1.0616x over previous
//
#include <hip/hip_runtime.h>

#define N_NODES 100000
#define N_EDGES 1250000
#define DIM 64
#define EDGE_DIM 10
#define BN_EPS 1e-5f

// workspace layout in ints: head[100000] | next[1250000] | sums (256 floats)
#define HEAD_OFF 0
#define NEXT_OFF N_NODES
#define SUMS_OFF_I (NEXT_OFF + N_EDGES)

// -----------------------------------------------------------------------------
// Build per-destination linked list: next[e] = old head[dst]; head[dst] = e.
// 1.25M int atomicExch over 400 KB (L2-resident) replaces 80M fp32 atomics.
// -----------------------------------------------------------------------------
extern "C" __global__ __launch_bounds__(256)
void build_ll_kernel(const int* __restrict__ ei,
                     int* __restrict__ head,
                     int* __restrict__ nxt)
{
    int e = blockIdx.x * 256 + threadIdx.x;
    if (e < N_EDGES) {
        unsigned dst = (unsigned)ei[N_EDGES + e];
        dst = dst < N_NODES ? dst : (N_NODES - 1);
        nxt[e] = atomicExch(&head[dst], e);
    }
}

// -----------------------------------------------------------------------------
// Fused kernel: per 64-node tile —
//   phase A: each wave (8 waves/block) walks the edge lists of 8 nodes,
//            lane = feature; h = x[v] + sum ReLU(x[src] + ea@We + be)
//            deposited transposed into LDS (sT[feat*68 + node]).
//   phase B: T = ReLU(H@W1+b1); R = ReLU(T@W2+b2) -> out; per-feature
//            sum/sumsq partials -> global atomics (128 per block).
// -----------------------------------------------------------------------------
extern "C" __global__ __launch_bounds__(512)
void node_fused_kernel(const float* __restrict__ x,
                       const int* __restrict__ ei,
                       const float* __restrict__ ea,
                       const float* __restrict__ We,
                       const float* __restrict__ be,
                       const int* __restrict__ head,
                       const int* __restrict__ nxt,
                       const float* __restrict__ W1,
                       const float* __restrict__ b1,
                       const float* __restrict__ W2,
                       const float* __restrict__ b2,
                       float* __restrict__ out,
                       float* __restrict__ sums)
{
    __shared__ __align__(16) float sW1[DIM * DIM];
    __shared__ __align__(16) float sW2[DIM * DIM];
    __shared__ __align__(16) float sT[DIM * 68];   // [feat][node], pad 68

    int tid  = threadIdx.x;
    int lane = tid & 63;
    int wv   = tid >> 6;          // wave 0..7
    int base = blockIdx.x * 64;

    for (int i = tid; i < DIM * DIM; i += 512) {
        sW1[i] = W1[i];
        sW2[i] = W2[i];
    }

    // loop-invariant: this lane's column of W_edge, and its bias
    float wcol[EDGE_DIM];
    #pragma unroll
    for (int k = 0; k < EDGE_DIM; ++k) wcol[k] = We[k * DIM + lane];
    float bias = be[lane];

    // ---- phase A: aggregation, 8 nodes per wave ----
    #pragma unroll 1
    for (int t = 0; t < 8; ++t) {
        int nl = wv * 8 + t;
        int v  = base + nl;
        float acc = 0.0f;
        if (v < N_NODES) {
            acc = x[(size_t)v * DIM + lane];
            int e = __builtin_amdgcn_readfirstlane(head[v]);
            while (e >= 0) {
                int en = __builtin_amdgcn_readfirstlane(nxt[e]);  // prefetch chain
                int s  = ei[e];                                   // scalar (e uniform)
                float m = bias;
                #pragma unroll
                for (int k = 0; k < EDGE_DIM; ++k)
                    m = fmaf(ea[(size_t)e * EDGE_DIM + k], wcol[k], m);
                m += x[(size_t)s * DIM + lane];
                acc += fmaxf(m, 0.0f);
                e = en;
            }
        }
        sT[lane * 68 + nl] = acc;   // H[node][feat] stored as sT[feat][node]
    }
    __syncthreads();

    // ---- phase B: two GEMMs, 4 nodes x 2 feats per thread ----
    int i0 = (tid & 15) * 4;   // node offset
    int j0 = (tid >> 4) * 2;   // feature offset (covers 0..62, each pair once)

    float acc1[4][2] = {};
    #pragma unroll 8
    for (int k = 0; k < DIM; ++k) {
        float4 av = *(const float4*)&sT[k * 68 + i0];
        float bw0 = sW1[k * DIM + j0];
        float bw1 = sW1[k * DIM + j0 + 1];
        float a4[4] = {av.x, av.y, av.z, av.w};
        #pragma unroll
        for (int a = 0; a < 4; ++a) {
            acc1[a][0] = fmaf(a4[a], bw0, acc1[a][0]);
            acc1[a][1] = fmaf(a4[a], bw1, acc1[a][1]);
        }
    }
    __syncthreads();   // all GEMM1 reads done before overwriting sT

    float b1a[2] = {b1[j0], b1[j0 + 1]};
    float tv[4][2];
    #pragma unroll
    for (int a = 0; a < 4; ++a)
        #pragma unroll
        for (int b = 0; b < 2; ++b)
            tv[a][b] = fmaxf(acc1[a][b] + b1a[b], 0.0f);

    #pragma unroll
    for (int b = 0; b < 2; ++b) {
        float4 w = make_float4(tv[0][b], tv[1][b], tv[2][b], tv[3][b]);
        *(float4*)&sT[(j0 + b) * 68 + i0] = w;   // T transposed back
    }
    __syncthreads();

    float acc2[4][2] = {};
    #pragma unroll 8
    for (int k = 0; k < DIM; ++k) {
        float4 av = *(const float4*)&sT[k * 68 + i0];
        float bw0 = sW2[k * DIM + j0];
        float bw1 = sW2[k * DIM + j0 + 1];
        float a4[4] = {av.x, av.y, av.z, av.w};
        #pragma unroll
        for (int a = 0; a < 4; ++a) {
            acc2[a][0] = fmaf(a4[a], bw0, acc2[a][0]);
            acc2[a][1] = fmaf(a4[a], bw1, acc2[a][1]);
        }
    }

    float b2a[2] = {b2[j0], b2[j0 + 1]};
    float ps[2] = {0.f, 0.f};
    float pq[2] = {0.f, 0.f};
    #pragma unroll
    for (int a = 0; a < 4; ++a) {
        int n = base + i0 + a;
        float r0 = fmaxf(acc2[a][0] + b2a[0], 0.0f);
        float r1 = fmaxf(acc2[a][1] + b2a[1], 0.0f);
        if (n < N_NODES) {
            float2 w = make_float2(r0, r1);
            *(float2*)&out[(size_t)n * DIM + j0] = w;
            ps[0] += r0; ps[1] += r1;
            pq[0] += r0 * r0; pq[1] += r1 * r1;
        }
    }

    // reduce over the 16-lane group sharing j0
    #pragma unroll
    for (int m = 1; m < 16; m <<= 1) {
        #pragma unroll
        for (int b = 0; b < 2; ++b) {
            ps[b] += __shfl_xor(ps[b], m, 64);
            pq[b] += __shfl_xor(pq[b], m, 64);
        }
    }
    if ((lane & 15) == 0) {
        #pragma unroll
        for (int b = 0; b < 2; ++b) {
            unsafeAtomicAdd(&sums[j0 + b], ps[b]);
            unsafeAtomicAdd(&sums[64 + j0 + b], pq[b]);
        }
    }
}

// -----------------------------------------------------------------------------
// BN stats: one block, 64 threads. scale/shift per feature.
// -----------------------------------------------------------------------------
extern "C" __global__ void bn_stats_kernel(float* __restrict__ sums,
                                           const float* __restrict__ gamma,
                                           const float* __restrict__ beta)
{
    int f = threadIdx.x;
    float inv_n = 1.0f / (float)N_NODES;
    float mean = sums[f] * inv_n;
    float var  = sums[64 + f] * inv_n - mean * mean;
    float sc   = gamma[f] * rsqrtf(var + BN_EPS);
    sums[128 + f] = sc;
    sums[192 + f] = beta[f] - mean * sc;
}

// -----------------------------------------------------------------------------
// BN apply: out = out*scale + shift, in place, float4.
// -----------------------------------------------------------------------------
extern "C" __global__ __launch_bounds__(256)
void bn_apply_kernel(float* __restrict__ out, const float* __restrict__ sums)
{
    int j = blockIdx.x * 256 + threadIdx.x;   // float4 index
    int f0 = (j & 15) * 4;
    float4 sc = *(const float4*)&sums[128 + f0];
    float4 sh = *(const float4*)&sums[192 + f0];
    float4 v = ((float4*)out)[j];
    v.x = fmaf(v.x, sc.x, sh.x);
    v.y = fmaf(v.y, sc.y, sh.y);
    v.z = fmaf(v.z, sc.z, sh.z);
    v.w = fmaf(v.w, sc.w, sh.w);
    ((float4*)out)[j] = v;
}

extern "C" void kernel_launch(void* const* d_in, const int* in_sizes, int n_in,
                              void* d_out, int out_size, void* d_ws, size_t ws_size,
                              hipStream_t stream)
{
    const float* x     = (const float*)d_in[0];
    const int*   ei    = (const int*)  d_in[1];
    const float* ea    = (const float*)d_in[2];
    const float* We    = (const float*)d_in[3];
    const float* be    = (const float*)d_in[4];
    const float* W1    = (const float*)d_in[5];
    const float* b1    = (const float*)d_in[6];
    const float* W2    = (const float*)d_in[7];
    const float* b2    = (const float*)d_in[8];
    const float* gamma = (const float*)d_in[9];
    const float* beta  = (const float*)d_in[10];

    float* out  = (float*)d_out;
    int*   wsi  = (int*)d_ws;
    int*   head = wsi + HEAD_OFF;
    int*   nxt  = wsi + NEXT_OFF;
    float* sums = (float*)(wsi + SUMS_OFF_I);

    hipMemsetAsync(head, 0xFF, (size_t)N_NODES * sizeof(int), stream);  // -1
    hipMemsetAsync(sums, 0, 256 * sizeof(float), stream);

    build_ll_kernel<<<(N_EDGES + 255) / 256, 256, 0, stream>>>(ei, head, nxt);

    node_fused_kernel<<<(N_NODES + 63) / 64, 512, 0, stream>>>(
        x, ei, ea, We, be, head, nxt, W1, b1, W2, b2, out, sums);

    bn_stats_kernel<<<1, 64, 0, stream>>>(sums, gamma, beta);

    bn_apply_kernel<<<(N_NODES * DIM / 4) / 256, 256, 0, stream>>>(out, sums);
}